// Round 1
// baseline (1023.766 us; speedup 1.0000x reference)
//
#include <hip/hip_runtime.h>

// LoRA linear, factored: t = x @ A^T  (M x 16), out = t @ B^T (M x 4096).
// M=16384, K=4096, N=4096, R=16. Memory-bound: read x (256 MiB) + write out (256 MiB).

#define M_TOTAL 16384
#define K_DIM 4096
#define N_DIM 4096
#define R_DIM 16
#define ROWS_PER_WAVE 4
#define ROWS_PER_BLOCK 16   // 4 waves * 4 rows
#define THREADS 256

__global__ __launch_bounds__(THREADS, 4)
void lora_fused_kernel(const float* __restrict__ x,
                       const float* __restrict__ A,    // [16][4096]
                       const float* __restrict__ Bm,   // [4096][16]
                       float* __restrict__ out)        // [16384][4096]
{
    __shared__ float t_lds[ROWS_PER_BLOCK][R_DIM];

    const int tid  = threadIdx.x;
    const int wave = tid >> 6;
    const int lane = tid & 63;
    const int block_row0 = blockIdx.x * ROWS_PER_BLOCK;
    const int wave_row0  = block_row0 + wave * ROWS_PER_WAVE;

    // ---------------- Phase 1: t = x @ A^T for this wave's 4 rows ----------------
    float acc[ROWS_PER_WAVE][R_DIM];
    #pragma unroll
    for (int w = 0; w < ROWS_PER_WAVE; ++w)
        #pragma unroll
        for (int r = 0; r < R_DIM; ++r) acc[w][r] = 0.0f;

    const float4* xrow0 = reinterpret_cast<const float4*>(x + (size_t)(wave_row0 + 0) * K_DIM);
    const float4* xrow1 = reinterpret_cast<const float4*>(x + (size_t)(wave_row0 + 1) * K_DIM);
    const float4* xrow2 = reinterpret_cast<const float4*>(x + (size_t)(wave_row0 + 2) * K_DIM);
    const float4* xrow3 = reinterpret_cast<const float4*>(x + (size_t)(wave_row0 + 3) * K_DIM);
    const float4* A4 = reinterpret_cast<const float4*>(A);

    #pragma unroll 1
    for (int j = 0; j < K_DIM / 256; ++j) {
        const int cidx = j * 64 + lane;     // float4 index within a row (coalesced per wave)
        float4 xv0 = xrow0[cidx];
        float4 xv1 = xrow1[cidx];
        float4 xv2 = xrow2[cidx];
        float4 xv3 = xrow3[cidx];
        #pragma unroll
        for (int r = 0; r < R_DIM; ++r) {
            float4 av = A4[(size_t)r * (K_DIM / 4) + cidx];
            acc[0][r] += xv0.x * av.x + xv0.y * av.y + xv0.z * av.z + xv0.w * av.w;
            acc[1][r] += xv1.x * av.x + xv1.y * av.y + xv1.z * av.z + xv1.w * av.w;
            acc[2][r] += xv2.x * av.x + xv2.y * av.y + xv2.z * av.z + xv2.w * av.w;
            acc[3][r] += xv3.x * av.x + xv3.y * av.y + xv3.z * av.z + xv3.w * av.w;
        }
    }

    // Wave-wide butterfly reduction (64 lanes) of all 64 partial sums.
    #pragma unroll
    for (int w = 0; w < ROWS_PER_WAVE; ++w) {
        #pragma unroll
        for (int r = 0; r < R_DIM; ++r) {
            float v = acc[w][r];
            v += __shfl_xor(v, 32, 64);
            v += __shfl_xor(v, 16, 64);
            v += __shfl_xor(v,  8, 64);
            v += __shfl_xor(v,  4, 64);
            v += __shfl_xor(v,  2, 64);
            v += __shfl_xor(v,  1, 64);
            acc[w][r] = v;
        }
    }
    if (lane == 0) {
        #pragma unroll
        for (int w = 0; w < ROWS_PER_WAVE; ++w)
            #pragma unroll
            for (int r = 0; r < R_DIM; ++r)
                t_lds[wave * ROWS_PER_WAVE + w][r] = acc[w][r];
    }
    __syncthreads();

    // ---------------- Phase 2: out = t @ B^T ----------------
    // Thread owns 4 consecutive output columns; 256 threads cover 1024 cols; 4 tiles.
    #pragma unroll 1
    for (int ot = 0; ot < N_DIM / 1024; ++ot) {
        const int o0 = ot * 1024 + tid * 4;

        float brow[4][R_DIM];           // B rows for my 4 output cols, kept in regs
        #pragma unroll
        for (int oo = 0; oo < 4; ++oo) {
            const float4* bp = reinterpret_cast<const float4*>(Bm + (size_t)(o0 + oo) * R_DIM);
            #pragma unroll
            for (int rc = 0; rc < 4; ++rc) {
                float4 b4 = bp[rc];
                brow[oo][rc * 4 + 0] = b4.x;
                brow[oo][rc * 4 + 1] = b4.y;
                brow[oo][rc * 4 + 2] = b4.z;
                brow[oo][rc * 4 + 3] = b4.w;
            }
        }

        #pragma unroll
        for (int m = 0; m < ROWS_PER_BLOCK; ++m) {
            float tv[R_DIM];
            const float4* tp = reinterpret_cast<const float4*>(&t_lds[m][0]);
            #pragma unroll
            for (int rc = 0; rc < 4; ++rc) {
                float4 t4 = tp[rc];      // broadcast read (all lanes same addr)
                tv[rc * 4 + 0] = t4.x;
                tv[rc * 4 + 1] = t4.y;
                tv[rc * 4 + 2] = t4.z;
                tv[rc * 4 + 3] = t4.w;
            }
            float4 oa;
            oa.x = 0.0f; oa.y = 0.0f; oa.z = 0.0f; oa.w = 0.0f;
            #pragma unroll
            for (int r = 0; r < R_DIM; ++r) {
                oa.x += tv[r] * brow[0][r];
                oa.y += tv[r] * brow[1][r];
                oa.z += tv[r] * brow[2][r];
                oa.w += tv[r] * brow[3][r];
            }
            float4* op = reinterpret_cast<float4*>(out + (size_t)(block_row0 + m) * N_DIM + o0);
            *op = oa;   // 256 threads -> 4 KB contiguous store per row
        }
    }
}

extern "C" void kernel_launch(void* const* d_in, const int* in_sizes, int n_in,
                              void* d_out, int out_size, void* d_ws, size_t ws_size,
                              hipStream_t stream) {
    const float* x  = (const float*)d_in[0];   // [4,4096,4096]
    const float* A  = (const float*)d_in[1];   // [16,4096]
    const float* Bm = (const float*)d_in[2];   // [4096,16]
    float* out = (float*)d_out;                // [4,4096,4096]

    dim3 grid(M_TOTAL / ROWS_PER_BLOCK);       // 1024 blocks
    dim3 block(THREADS);
    lora_fused_kernel<<<grid, block, 0, stream>>>(x, A, Bm, out);
}

// Round 2
// 688.772 us; speedup vs baseline: 1.4864x; 1.4864x over previous
//
#include <hip/hip_runtime.h>

// LoRA linear, factored: t = x @ A^T  (M x 16), out = t @ B^T (M x 4096).
// Memory-bound: read x (256 MiB) + write out (256 MiB). R=16.
//
// R1 lesson: __launch_bounds__(256,4) capped VGPRs below the ~100-reg working
// set -> scratch spills in the K-loop -> 1.3 GiB of spill traffic and 743 us.
// Fix: (256,2) gives the allocator room (cap 256). Also: nontemporal x loads /
// out stores keep the streaming 512 MiB from evicting L2-resident A and B.

typedef float f4 __attribute__((ext_vector_type(4)));

#define M_TOTAL 16384
#define K_DIM 4096
#define N_DIM 4096
#define R_DIM 16
#define ROWS_PER_WAVE 4
#define ROWS_PER_BLOCK 16   // 4 waves * 4 rows
#define THREADS 256

__global__ __launch_bounds__(THREADS, 2)
void lora_fused_kernel(const float* __restrict__ x,
                       const float* __restrict__ A,    // [16][4096]
                       const float* __restrict__ Bm,   // [4096][16]
                       float* __restrict__ out)        // [16384][4096]
{
    __shared__ float t_lds[ROWS_PER_BLOCK][R_DIM];

    const int tid  = threadIdx.x;
    const int wave = tid >> 6;
    const int lane = tid & 63;
    const int block_row0 = blockIdx.x * ROWS_PER_BLOCK;
    const int wave_row0  = block_row0 + wave * ROWS_PER_WAVE;

    // ---------------- Phase 1: t = x @ A^T for this wave's 4 rows ----------------
    float acc[ROWS_PER_WAVE][R_DIM];
    #pragma unroll
    for (int w = 0; w < ROWS_PER_WAVE; ++w)
        #pragma unroll
        for (int r = 0; r < R_DIM; ++r) acc[w][r] = 0.0f;

    const f4* xrow0 = reinterpret_cast<const f4*>(x + (size_t)(wave_row0 + 0) * K_DIM);
    const f4* xrow1 = reinterpret_cast<const f4*>(x + (size_t)(wave_row0 + 1) * K_DIM);
    const f4* xrow2 = reinterpret_cast<const f4*>(x + (size_t)(wave_row0 + 2) * K_DIM);
    const f4* xrow3 = reinterpret_cast<const f4*>(x + (size_t)(wave_row0 + 3) * K_DIM);
    const f4* A4 = reinterpret_cast<const f4*>(A);

    #pragma unroll 1
    for (int j = 0; j < K_DIM / 256; ++j) {
        const int cidx = j * 64 + lane;     // float4 index within a row (coalesced per wave)
        f4 xv0 = __builtin_nontemporal_load(&xrow0[cidx]);
        f4 xv1 = __builtin_nontemporal_load(&xrow1[cidx]);
        f4 xv2 = __builtin_nontemporal_load(&xrow2[cidx]);
        f4 xv3 = __builtin_nontemporal_load(&xrow3[cidx]);
        #pragma unroll
        for (int r = 0; r < R_DIM; ++r) {
            f4 av = A4[(size_t)r * (K_DIM / 4) + cidx];   // cacheable: A is L2-hot
            acc[0][r] += xv0[0] * av[0] + xv0[1] * av[1] + xv0[2] * av[2] + xv0[3] * av[3];
            acc[1][r] += xv1[0] * av[0] + xv1[1] * av[1] + xv1[2] * av[2] + xv1[3] * av[3];
            acc[2][r] += xv2[0] * av[0] + xv2[1] * av[1] + xv2[2] * av[2] + xv2[3] * av[3];
            acc[3][r] += xv3[0] * av[0] + xv3[1] * av[1] + xv3[2] * av[2] + xv3[3] * av[3];
        }
    }

    // Wave-wide butterfly reduction (64 lanes) of all partial sums.
    #pragma unroll
    for (int w = 0; w < ROWS_PER_WAVE; ++w) {
        #pragma unroll
        for (int r = 0; r < R_DIM; ++r) {
            float v = acc[w][r];
            v += __shfl_xor(v, 32, 64);
            v += __shfl_xor(v, 16, 64);
            v += __shfl_xor(v,  8, 64);
            v += __shfl_xor(v,  4, 64);
            v += __shfl_xor(v,  2, 64);
            v += __shfl_xor(v,  1, 64);
            acc[w][r] = v;
        }
    }
    if (lane == 0) {
        #pragma unroll
        for (int w = 0; w < ROWS_PER_WAVE; ++w)
            #pragma unroll
            for (int r = 0; r < R_DIM; ++r)
                t_lds[wave * ROWS_PER_WAVE + w][r] = acc[w][r];
    }
    __syncthreads();

    // ---------------- Phase 2: out = t @ B^T ----------------
    // Thread owns 4 consecutive output columns; 256 threads cover 1024 cols; 4 tiles.
    #pragma unroll 1
    for (int ot = 0; ot < N_DIM / 1024; ++ot) {
        const int o0 = ot * 1024 + tid * 4;

        float brow[4][R_DIM];           // B rows for my 4 output cols, kept in regs
        #pragma unroll
        for (int oo = 0; oo < 4; ++oo) {
            const f4* bp = reinterpret_cast<const f4*>(Bm + (size_t)(o0 + oo) * R_DIM);
            #pragma unroll
            for (int rc = 0; rc < 4; ++rc) {
                f4 b4 = bp[rc];         // cacheable: B is L2-hot
                brow[oo][rc * 4 + 0] = b4[0];
                brow[oo][rc * 4 + 1] = b4[1];
                brow[oo][rc * 4 + 2] = b4[2];
                brow[oo][rc * 4 + 3] = b4[3];
            }
        }

        #pragma unroll
        for (int m = 0; m < ROWS_PER_BLOCK; ++m) {
            float tv[R_DIM];
            const f4* tp = reinterpret_cast<const f4*>(&t_lds[m][0]);
            #pragma unroll
            for (int rc = 0; rc < 4; ++rc) {
                f4 t4 = tp[rc];          // LDS broadcast read
                tv[rc * 4 + 0] = t4[0];
                tv[rc * 4 + 1] = t4[1];
                tv[rc * 4 + 2] = t4[2];
                tv[rc * 4 + 3] = t4[3];
            }
            f4 oa = {0.0f, 0.0f, 0.0f, 0.0f};
            #pragma unroll
            for (int r = 0; r < R_DIM; ++r) {
                oa[0] += tv[r] * brow[0][r];
                oa[1] += tv[r] * brow[1][r];
                oa[2] += tv[r] * brow[2][r];
                oa[3] += tv[r] * brow[3][r];
            }
            f4* op = reinterpret_cast<f4*>(out + (size_t)(block_row0 + m) * N_DIM + o0);
            __builtin_nontemporal_store(oa, op);   // streaming store, don't pollute L2
        }
    }
}

extern "C" void kernel_launch(void* const* d_in, const int* in_sizes, int n_in,
                              void* d_out, int out_size, void* d_ws, size_t ws_size,
                              hipStream_t stream) {
    const float* x  = (const float*)d_in[0];   // [4,4096,4096]
    const float* A  = (const float*)d_in[1];   // [16,4096]
    const float* Bm = (const float*)d_in[2];   // [4096,16]
    float* out = (float*)d_out;                // [4,4096,4096]

    dim3 grid(M_TOTAL / ROWS_PER_BLOCK);       // 1024 blocks
    dim3 block(THREADS);
    lora_fused_kernel<<<grid, block, 0, stream>>>(x, A, Bm, out);
}